// Round 2
// baseline (735.768 us; speedup 1.0000x reference)
//
#include <hip/hip_runtime.h>
#include <hip/hip_bf16.h>

#define LF 64
#define NBAGS 5
#define BROWS 2048
#define OUTC 320
#define CHUNK 2048
#define BM 64
#define BK 64
#define WS_SUMS_BYTES 65536

typedef __attribute__((ext_vector_type(8))) short short8;
typedef __attribute__((ext_vector_type(4))) float f32x4;

struct BagArgs {
    const int*   A[NBAGS];
    const float* W[NBAGS];
    int K[NBAGS];
    int cstart[NBAGS + 1];   // chunk prefix (CHUNK granularity)
    int tstart[NBAGS + 1];   // 64-k tile prefix
};

__device__ __forceinline__ unsigned short f2bf(float f) {
    unsigned u = __float_as_uint(f);
    u += 0x7FFFu + ((u >> 16) & 1u);   // round-to-nearest-even
    return (unsigned short)(u >> 16);
}

__device__ __forceinline__ unsigned ones2(int x, int y) {
    return (x ? 0x3F80u : 0u) | (y ? 0x3F800000u : 0u);
}

// Pack W (f32, [K][64]) -> bf16 fragment-major 64-k tiles:
// tile byte layout: ushort idx = ((k>>3)*64 + c)*8 + (k&7)   (8 KB per tile)
// One wave per tile; lane owns column c.
__global__ __launch_bounds__(256) void pack_w(BagArgs args,
                                              unsigned short* __restrict__ Wp) {
    __shared__ unsigned short ls[4][4096];
    const int wv = threadIdx.x >> 6;
    const int c  = threadIdx.x & 63;
    const int gtile = blockIdx.x * 4 + wv;

    int bag = 0;
#pragma unroll
    for (int b = 1; b < NBAGS; ++b)
        if (gtile >= args.tstart[b]) bag = b;
    const int lt = gtile - args.tstart[bag];
    const float* __restrict__ W = args.W[bag];
    const int K = args.K[bag];

    unsigned short* L = ls[wv];
#pragma unroll 8
    for (int k = 0; k < 64; ++k) {
        const int gk = lt * 64 + k;
        float v = (gk < K) ? W[(size_t)gk * LF + c] : 0.f;
        L[(((k >> 3) * LF) + c) * 8 + (k & 7)] = f2bf(v);
    }
    __syncthreads();
    unsigned short* dst = Wp + ((size_t)gtile << 12);
#pragma unroll
    for (int j = 0; j < 8; ++j)
        *(short8*)(dst + c * 8 + j * 512) = *(const short8*)(L + c * 8 + j * 512);
}

template<bool PACKED>
__global__ __launch_bounds__(256, 4) void bag_gemm(BagArgs args,
                                                   const unsigned short* __restrict__ Wp,
                                                   float* __restrict__ out,
                                                   int* __restrict__ sums)
{
    __shared__ unsigned short lsB[2][BK * LF];   // 2 x 8 KB, fragment-major

    const int tid  = threadIdx.x;
    const int wave = tid >> 6;
    const int lane = tid & 63;
    const int fr   = lane & 15;
    const int kg   = lane >> 4;

    int y = blockIdx.y, bag = 0;
#pragma unroll
    for (int b = 1; b < NBAGS; ++b)
        if (y >= args.cstart[b]) bag = b;
    const int chunk  = y - args.cstart[bag];
    const int K      = args.K[bag];
    const int k0     = chunk * CHUNK;
    const int kend   = min(k0 + CHUNK, K);
    const int niters = (kend - k0 + BK - 1) >> 6;
    const int tile0  = args.tstart[bag] + chunk * (CHUNK / BK);

    const int m0  = blockIdx.x * BM;
    const int row = m0 + wave * 16 + fr;            // lane's A row (== its 16-row strip)
    const int* __restrict__ pA = args.A[bag] + (size_t)row * K;
    const float* __restrict__ W = args.W[bag];

    f32x4 acc[4];
#pragma unroll
    for (int i = 0; i < 4; ++i) acc[i] = (f32x4){0.f, 0.f, 0.f, 0.f};
    int psum = 0;

    auto loadA = [&](int t, int4& x0, int4& x1, int4& x2, int4& x3) {
        const int c0 = k0 + t * BK + kg * 8;   // all K are multiples of 4
        const int c1 = c0 + 32;
        const int4 z = make_int4(0, 0, 0, 0);
        x0 = (c0     < kend) ? *(const int4*)(pA + c0)     : z;
        x1 = (c0 + 4 < kend) ? *(const int4*)(pA + c0 + 4) : z;
        x2 = (c1     < kend) ? *(const int4*)(pA + c1)     : z;
        x3 = (c1 + 4 < kend) ? *(const int4*)(pA + c1 + 4) : z;
    };

    auto stageW = [&](int t, int buf) {
        if constexpr (PACKED) {
            // tile image == LDS image; linear DMA, 1 KB per instruction per wave
            const char* src = (const char*)Wp + (((size_t)(tile0 + t)) << 13)
                              + wave * 2048 + lane * 16;            // per-lane global
            char* dst = (char*)&lsB[buf][0] + wave * 2048;          // wave-uniform LDS
            __builtin_amdgcn_global_load_lds(
                (const __attribute__((address_space(1))) void*)src,
                (__attribute__((address_space(3))) void*)dst, 16, 0, 0);
            __builtin_amdgcn_global_load_lds(
                (const __attribute__((address_space(1))) void*)(src + 1024),
                (__attribute__((address_space(3))) void*)(dst + 1024), 16, 0, 0);
        } else {
            const int kq = tid >> 4, cg = tid & 15;
#pragma unroll
            for (int u = 0; u < 4; ++u) {
                const int k  = kq * 4 + u;
                const int gk = k0 + t * BK + k;
                float4 w = make_float4(0.f, 0.f, 0.f, 0.f);
                if (gk < kend) w = *(const float4*)(W + (size_t)gk * LF + cg * 4);
                unsigned short* d = &lsB[buf][(((k >> 3) * LF) + cg * 4) * 8 + (k & 7)];
                d[0]  = f2bf(w.x);
                d[8]  = f2bf(w.y);
                d[16] = f2bf(w.z);
                d[24] = f2bf(w.w);
            }
        }
    };

    int4 a0, a1, a2, a3;
    loadA(0, a0, a1, a2, a3);
    stageW(0, 0);
    if constexpr (PACKED) asm volatile("s_waitcnt vmcnt(0)" ::: "memory");
    __syncthreads();

    for (int t = 0; t < niters; ++t) {
        const int cur = t & 1;
        int4 n0, n1, n2, n3;
        if (t + 1 < niters) {
            loadA(t + 1, n0, n1, n2, n3);      // fire A prefetch (regs)
            stageW(t + 1, cur ^ 1);            // fire W prefetch (DMA to other buf)
        } else {
            n0 = n1 = n2 = n3 = make_int4(0, 0, 0, 0);
        }

        psum += a0.x + a0.y + a0.z + a0.w + a1.x + a1.y + a1.z + a1.w
              + a2.x + a2.y + a2.z + a2.w + a3.x + a3.y + a3.z + a3.w;

        int4 u0 = make_int4(ones2(a0.x, a0.y), ones2(a0.z, a0.w),
                            ones2(a1.x, a1.y), ones2(a1.z, a1.w));
        int4 u1 = make_int4(ones2(a2.x, a2.y), ones2(a2.z, a2.w),
                            ones2(a3.x, a3.y), ones2(a3.z, a3.w));
        short8 fa0 = *(short8*)&u0;
        short8 fa1 = *(short8*)&u1;

        const unsigned short* Lb = &lsB[cur][0];
#pragma unroll
        for (int ni = 0; ni < 4; ++ni) {
            short8 fb = *(const short8*)(Lb + ((0 * 4 + kg) * LF + ni * 16 + fr) * 8);
            acc[ni] = __builtin_amdgcn_mfma_f32_16x16x32_bf16(fa0, fb, acc[ni], 0, 0, 0);
        }
#pragma unroll
        for (int ni = 0; ni < 4; ++ni) {
            short8 fb = *(const short8*)(Lb + ((1 * 4 + kg) * LF + ni * 16 + fr) * 8);
            acc[ni] = __builtin_amdgcn_mfma_f32_16x16x32_bf16(fa1, fb, acc[ni], 0, 0, 0);
        }

        a0 = n0; a1 = n1; a2 = n2; a3 = n3;
        if constexpr (PACKED) asm volatile("s_waitcnt vmcnt(0)" ::: "memory");
        __syncthreads();
    }

    // row popcount: lanes (fr, kg=0..3) hold k-slices of the same row
    psum += __shfl_xor(psum, 16);
    psum += __shfl_xor(psum, 32);
    if (kg == 0) atomicAdd(&sums[bag * BROWS + row], psum);

    // C/D layout: col = lane&15, row = (lane>>4)*4 + reg   [validated R1]
    const int rg = lane >> 4;
    const int colb = bag * LF;
#pragma unroll
    for (int ni = 0; ni < 4; ++ni)
#pragma unroll
        for (int r = 0; r < 4; ++r)
            atomicAdd(&out[(size_t)(m0 + wave * 16 + rg * 4 + r) * OUTC + colb + ni * 16 + fr],
                      acc[ni][r]);
}

__global__ __launch_bounds__(256) void norm_fix(float* __restrict__ out,
                                                const int* __restrict__ sums) {
    const int idx = blockIdx.x * blockDim.x + threadIdx.x;
    if (idx >= BROWS * OUTC) return;
    const int m = idx / OUTC;
    const int c = idx % OUTC;
    const int bag = c >> 6;
    float v = out[idx];
    if (bag == 0) {
        // faithful reference bug: decades normalized by dec sums AND movie sums
        const int s0 = sums[m];
        const int s1 = sums[BROWS + m];
        if (s0) v /= (float)s0;
        if (s1) v /= (float)s1;
    } else if (bag >= 2) {
        const int s = sums[bag * BROWS + m];
        if (s) v /= (float)s;
    }
    out[idx] = v;
}

extern "C" void kernel_launch(void* const* d_in, const int* in_sizes, int n_in,
                              void* d_out, int out_size, void* d_ws, size_t ws_size,
                              hipStream_t stream) {
    float* out = (float*)d_out;
    int* sums = (int*)d_ws;
    unsigned short* Wp = (unsigned short*)((char*)d_ws + WS_SUMS_BYTES);

    hipMemsetAsync(d_out, 0, (size_t)out_size * sizeof(float), stream);
    hipMemsetAsync(sums, 0, NBAGS * BROWS * sizeof(int), stream);

    BagArgs args;
    const int Ks[NBAGS] = {12, 60000, 32, 100000, 20000};
    int ccum = 0, tcum = 0;
    for (int b = 0; b < NBAGS; ++b) {
        args.A[b] = (const int*)d_in[b];
        args.W[b] = (const float*)d_in[5 + b];
        args.K[b] = Ks[b];
        args.cstart[b] = ccum;
        args.tstart[b] = tcum;
        ccum += (Ks[b] + CHUNK - 1) / CHUNK;   // -> 91
        tcum += (Ks[b] + BK - 1) / BK;         // -> 2816
    }
    args.cstart[NBAGS] = ccum;
    args.tstart[NBAGS] = tcum;

    const size_t need = WS_SUMS_BYTES + (size_t)tcum * (size_t)(BK * LF) * sizeof(unsigned short);
    const bool packed = (ws_size >= need) && (tcum % 4 == 0);

    dim3 grid(BROWS / BM, ccum);
    if (packed) {
        pack_w<<<tcum / 4, 256, 0, stream>>>(args, Wp);
        bag_gemm<true><<<grid, 256, 0, stream>>>(args, Wp, out, sums);
    } else {
        bag_gemm<false><<<grid, 256, 0, stream>>>(args, Wp, out, sums);
    }

    norm_fix<<<(BROWS * OUTC + 255) / 256, 256, 0, stream>>>(out, sums);
}

// Round 3
// 516.818 us; speedup vs baseline: 1.4236x; 1.4236x over previous
//
#include <hip/hip_runtime.h>
#include <hip/hip_bf16.h>

#define LF 64
#define NBAGS 5
#define BROWS 2048
#define OUTC 320
#define KC 4096
#define MT 64

#define WS_SUMS_BYTES 65536
#define WP_BYTES 23068672ull          // 2816 tiles * 8192 B
#define PART_OFF (WS_SUMS_BYTES + WP_BYTES)
#define NCHUNKS 46                    // bags 1..4 only (15+1+25+5)
#define PART_BYTES ((size_t)NCHUNKS * BROWS * LF * 4)

typedef __attribute__((ext_vector_type(8))) short short8;
typedef __attribute__((ext_vector_type(4))) float f32x4;

struct BagArgs {
    const int*   A[NBAGS];
    const float* W[NBAGS];
    int K[NBAGS];
    int cstart[NBAGS + 1];   // KC-chunk prefix, bags 1..4 (bag0 has none)
    int tstart[NBAGS + 1];   // 64-k tile prefix (all bags, incl. dec)
};

__device__ __forceinline__ unsigned short f2bf(float f) {
    unsigned u = __float_as_uint(f);
    u += 0x7FFFu + ((u >> 16) & 1u);   // round-to-nearest-even
    return (unsigned short)(u >> 16);
}

// Pack W (f32 [K][64]) -> bf16 fragment-major 64-k tiles (8 KB each):
// short index within tile = ((k>>3)*64 + c)*8 + (k&7). Zero-filled past K.
__global__ __launch_bounds__(256) void pack_w(BagArgs args,
                                              unsigned short* __restrict__ Wp) {
    __shared__ unsigned short ls[4][4096];
    const int wv = threadIdx.x >> 6;
    const int c  = threadIdx.x & 63;
    const int gtile = blockIdx.x * 4 + wv;

    int bag = 0;
#pragma unroll
    for (int b = 1; b < NBAGS; ++b)
        if (gtile >= args.tstart[b]) bag = b;
    const int lt = gtile - args.tstart[bag];
    const float* __restrict__ W = args.W[bag];
    const int K = args.K[bag];

    unsigned short* L = ls[wv];
#pragma unroll 8
    for (int k = 0; k < 64; ++k) {
        const int gk = lt * 64 + k;
        float v = (gk < K) ? W[(size_t)gk * LF + c] : 0.f;
        L[(((k >> 3) * LF) + c) * 8 + (k & 7)] = f2bf(v);
    }
    __syncthreads();
    unsigned short* dst = Wp + ((size_t)gtile << 12);
#pragma unroll
    for (int j = 0; j < 8; ++j)
        *(short8*)(dst + c * 8 + j * 512) = *(const short8*)(L + c * 8 + j * 512);
}

// MODE 0: partials to ws. MODE 1: atomicAdd into out. MODE 2: emergency,
// unpacked W (strided f32) + atomics. No LDS, no barriers in any mode.
template<int MODE>
__global__ __launch_bounds__(256, 4) void bag_gemm(BagArgs args,
                                                   const unsigned short* __restrict__ Wp,
                                                   float* __restrict__ dstbuf,
                                                   int* __restrict__ sums)
{
    const int tid  = threadIdx.x;
    const int wave = tid >> 6;
    const int lane = tid & 63;
    const int fr   = lane & 15;
    const int kg   = lane >> 4;

    const int g  = blockIdx.x >> 5;    // global chunk (bags 1..4)
    const int mt = blockIdx.x & 31;    // m-tile (64 rows)

    int bag = 1;
#pragma unroll
    for (int b = 2; b < NBAGS; ++b)
        if (g >= args.cstart[b]) bag = b;
    const int chunk  = g - args.cstart[bag];
    const int K      = args.K[bag];
    const int kc0    = chunk * KC;
    const int nsteps = (min(kc0 + KC, K) - kc0) >> 5;   // always exact (K%32==0 for bags 1..4)

    const int row0 = mt * MT + wave * 16;
    const int row  = row0 + fr;
    const int* __restrict__ pA = args.A[bag] + (size_t)row * K + kc0 + kg * 8;
    const unsigned short* __restrict__ pB =
        Wp + ((size_t)(args.tstart[bag] + chunk * (KC / 64)) << 12) + (kg * LF + fr) * 8;
    const float* __restrict__ Wf = args.W[bag];

    f32x4 acc[4];
#pragma unroll
    for (int i = 0; i < 4; ++i) acc[i] = (f32x4){0.f, 0.f, 0.f, 0.f};
    int psum = 0;

    auto loadA = [&](int s, int4& x0, int4& x1) {
        const int* p = pA + s * 32;
        x0 = *(const int4*)(p);
        x1 = *(const int4*)(p + 4);
    };
    auto loadB = [&](int s, short8& o0, short8& o1, short8& o2, short8& o3) {
        if constexpr (MODE < 2) {
            const unsigned short* p = pB + (size_t)s * 2048;  // +4 KB per 32-k step
            o0 = *(const short8*)(p);
            o1 = *(const short8*)(p + 128);
            o2 = *(const short8*)(p + 256);
            o3 = *(const short8*)(p + 384);
        } else {
            const int kb = kc0 + s * 32 + kg * 8;
            short8 o[4];
#pragma unroll
            for (int ni = 0; ni < 4; ++ni) {
                unsigned short t[8];
#pragma unroll
                for (int j = 0; j < 8; ++j)
                    t[j] = f2bf(Wf[(size_t)(kb + j) * LF + ni * 16 + fr]);
                o[ni] = *(short8*)t;
            }
            o0 = o[0]; o1 = o[1]; o2 = o[2]; o3 = o[3];
        }
    };

    int4 a0, a1;
    short8 b0, b1, b2, b3;
    loadA(0, a0, a1);
    loadB(0, b0, b1, b2, b3);

    for (int s = 0; s < nsteps; ++s) {
        int4 na0 = make_int4(0, 0, 0, 0), na1 = na0;
        short8 nb0 = {}, nb1 = {}, nb2 = {}, nb3 = {};
        if (s + 1 < nsteps) {
            loadA(s + 1, na0, na1);
            loadB(s + 1, nb0, nb1, nb2, nb3);
        }

        psum += a0.x + a0.y + a0.z + a0.w + a1.x + a1.y + a1.z + a1.w;

        // ints are exactly {0,1}: (x | y<<16) * 0x3F80 = bf16(x) | bf16(y)<<16
        unsigned p0 = (unsigned)(a0.x | (a0.y << 16)) * 0x3F80u;
        unsigned p1 = (unsigned)(a0.z | (a0.w << 16)) * 0x3F80u;
        unsigned p2 = (unsigned)(a1.x | (a1.y << 16)) * 0x3F80u;
        unsigned p3 = (unsigned)(a1.z | (a1.w << 16)) * 0x3F80u;
        int4 u = make_int4((int)p0, (int)p1, (int)p2, (int)p3);
        short8 fa = *(short8*)&u;

        acc[0] = __builtin_amdgcn_mfma_f32_16x16x32_bf16(fa, b0, acc[0], 0, 0, 0);
        acc[1] = __builtin_amdgcn_mfma_f32_16x16x32_bf16(fa, b1, acc[1], 0, 0, 0);
        acc[2] = __builtin_amdgcn_mfma_f32_16x16x32_bf16(fa, b2, acc[2], 0, 0, 0);
        acc[3] = __builtin_amdgcn_mfma_f32_16x16x32_bf16(fa, b3, acc[3], 0, 0, 0);

        a0 = na0; a1 = na1;
        b0 = nb0; b1 = nb1; b2 = nb2; b3 = nb3;
    }

    // row popcount: combine the 4 kg slices of each row
    psum += __shfl_xor(psum, 16);
    psum += __shfl_xor(psum, 32);
    if (kg == 0) atomicAdd(&sums[bag * BROWS + row], psum);

    // C/D: col = lane&15 (=fr), row = kg*4 + reg   [validated R1/R2]
    if constexpr (MODE == 0) {
        float* dst = dstbuf + ((size_t)g * BROWS + row0 + kg * 4) * LF + fr;
#pragma unroll
        for (int ni = 0; ni < 4; ++ni)
#pragma unroll
            for (int r = 0; r < 4; ++r)
                dst[(size_t)r * LF + ni * 16] = acc[ni][r];
    } else {
#pragma unroll
        for (int ni = 0; ni < 4; ++ni)
#pragma unroll
            for (int r = 0; r < 4; ++r)
                atomicAdd(dstbuf + (size_t)(row0 + kg * 4 + r) * OUTC + bag * LF + ni * 16 + fr,
                          acc[ni][r]);
    }
}

// Sum split-K partials (or read accumulated out), apply normalization
// (incl. the faithful "decades divided twice" bug), and compute the tiny
// K=12 decades bag directly in f32.
template<bool FROMPART>
__global__ __launch_bounds__(256) void reduce_norm(BagArgs args,
                                                   const float* __restrict__ part,
                                                   float* __restrict__ out,
                                                   const int* __restrict__ sums)
{
    const int idx = blockIdx.x * 256 + threadIdx.x;
    if (idx >= BROWS * OUTC) return;
    const int row = idx / OUTC;
    const int c   = idx - row * OUTC;
    const int bag = c >> 6;
    const int col = c & 63;

    float v;
    if (bag == 0) {
        const int*   A0 = args.A[0];
        const float* W0 = args.W[0];
        float a = 0.f; int s = 0;
#pragma unroll
        for (int k = 0; k < 12; ++k) {
            const int x = A0[row * 12 + k];
            s += x;
            if (x) a += W0[k * LF + col];
        }
        if (s) a /= (float)s;
        const int sm = sums[1 * BROWS + row];     // ref bug: also divide by movie sum
        if (sm) a /= (float)sm;
        v = a;
    } else {
        if constexpr (FROMPART) {
            float a = 0.f;
            for (int gg = args.cstart[bag]; gg < args.cstart[bag + 1]; ++gg)
                a += part[((size_t)gg * BROWS + row) * LF + col];
            v = a;
        } else {
            v = out[idx];
        }
        if (bag >= 2) {
            const int s = sums[bag * BROWS + row];
            if (s) v /= (float)s;
        }
        // bag 1 (movies): never normalized (faithful to reference bug)
    }
    out[idx] = v;
}

extern "C" void kernel_launch(void* const* d_in, const int* in_sizes, int n_in,
                              void* d_out, int out_size, void* d_ws, size_t ws_size,
                              hipStream_t stream) {
    float* out = (float*)d_out;
    int* sums = (int*)d_ws;
    unsigned short* Wp = (unsigned short*)((char*)d_ws + WS_SUMS_BYTES);
    float* part = (float*)((char*)d_ws + PART_OFF);

    BagArgs args;
    const int Ks[NBAGS] = {12, 60000, 32, 100000, 20000};
    int tcum = 0;
    for (int b = 0; b < NBAGS; ++b) {
        args.A[b] = (const int*)d_in[b];
        args.W[b] = (const float*)d_in[5 + b];
        args.K[b] = Ks[b];
        args.tstart[b] = tcum;
        tcum += (Ks[b] + 63) / 64;          // -> 2816
    }
    args.tstart[NBAGS] = tcum;
    args.cstart[0] = 0;
    int ccum = 0;
    for (int b = 1; b < NBAGS; ++b) {
        args.cstart[b] = ccum;
        ccum += (Ks[b] + KC - 1) / KC;      // 15 + 1 + 25 + 5 = 46
    }
    args.cstart[NBAGS] = ccum;

    hipMemsetAsync(sums, 0, NBAGS * BROWS * sizeof(int), stream);

    const bool have_wp   = ws_size >= (size_t)WS_SUMS_BYTES + WP_BYTES;
    const bool have_part = ws_size >= PART_OFF + PART_BYTES;

    if (have_wp)
        pack_w<<<tcum / 4, 256, 0, stream>>>(args, Wp);

    dim3 grid(NCHUNKS * 32);
    if (have_wp && have_part) {
        bag_gemm<0><<<grid, 256, 0, stream>>>(args, Wp, part, sums);
        reduce_norm<true><<<(BROWS * OUTC + 255) / 256, 256, 0, stream>>>(args, part, out, sums);
    } else if (have_wp) {
        hipMemsetAsync(d_out, 0, (size_t)out_size * sizeof(float), stream);
        bag_gemm<1><<<grid, 256, 0, stream>>>(args, Wp, out, sums);
        reduce_norm<false><<<(BROWS * OUTC + 255) / 256, 256, 0, stream>>>(args, part, out, sums);
    } else {
        hipMemsetAsync(d_out, 0, (size_t)out_size * sizeof(float), stream);
        bag_gemm<2><<<grid, 256, 0, stream>>>(args, Wp, out, sums);
        reduce_norm<false><<<(BROWS * OUTC + 255) / 256, 256, 0, stream>>>(args, part, out, sums);
    }
}

// Round 4
// 406.945 us; speedup vs baseline: 1.8080x; 1.2700x over previous
//
#include <hip/hip_runtime.h>
#include <hip/hip_bf16.h>

#define LF 64
#define NBAGS 5
#define BROWS 2048
#define OUTC 320
#define KC 2048
#define MT_BLOCK 128               // rows per block: 4 waves x 32 rows
#define NMT (BROWS / MT_BLOCK)     // 16

#define WS_SUMS_BYTES 65536
#define WP_BYTES 23068672ull       // 2816 tiles * 8192 B
#define PART_OFF (WS_SUMS_BYTES + WP_BYTES)
#define NCHUNKS 90                 // bags 1..4: 30 + 1 + 49 + 10
#define PART_BYTES ((size_t)NCHUNKS * BROWS * LF * 4)

typedef __attribute__((ext_vector_type(8))) short short8;
typedef __attribute__((ext_vector_type(4))) float f32x4;

struct BagArgs {
    const int*   A[NBAGS];
    const float* W[NBAGS];
    int K[NBAGS];
    int cstart[NBAGS + 1];   // KC-chunk prefix, bags 1..4
    int tstart[NBAGS + 1];   // 64-k tile prefix, all bags
};

__device__ __forceinline__ unsigned short f2bf(float f) {
    unsigned u = __float_as_uint(f);
    u += 0x7FFFu + ((u >> 16) & 1u);   // round-to-nearest-even
    return (unsigned short)(u >> 16);
}

// Pack W (f32 [K][64]) -> bf16 fragment-major 64-k tiles (8 KB each):
// short index within tile = ((k>>3)*64 + c)*8 + (k&7). Zero-filled past K.
__global__ __launch_bounds__(256) void pack_w(BagArgs args,
                                              unsigned short* __restrict__ Wp) {
    __shared__ unsigned short ls[4][4096];
    const int wv = threadIdx.x >> 6;
    const int c  = threadIdx.x & 63;
    const int gtile = blockIdx.x * 4 + wv;

    int bag = 0;
#pragma unroll
    for (int b = 1; b < NBAGS; ++b)
        if (gtile >= args.tstart[b]) bag = b;
    const int lt = gtile - args.tstart[bag];
    const float* __restrict__ W = args.W[bag];
    const int K = args.K[bag];

    unsigned short* L = ls[wv];
#pragma unroll 8
    for (int k = 0; k < 64; ++k) {
        const int gk = lt * 64 + k;
        float v = (gk < K) ? W[(size_t)gk * LF + c] : 0.f;
        L[(((k >> 3) * LF) + c) * 8 + (k & 7)] = f2bf(v);
    }
    __syncthreads();
    unsigned short* dst = Wp + ((size_t)gtile << 12);
#pragma unroll
    for (int j = 0; j < 8; ++j)
        *(short8*)(dst + c * 8 + j * 512) = *(const short8*)(L + c * 8 + j * 512);
}

// MODE 0: partials to ws (plain stores). MODE 1: atomicAdd into out.
// MODE 2: emergency, unpacked f32 W + atomics. No LDS, no barriers.
template<int MODE>
__global__ __launch_bounds__(256) void bag_gemm(BagArgs args,
                                                const unsigned short* __restrict__ Wp,
                                                float* __restrict__ dstbuf,
                                                int* __restrict__ sums)
{
    const int tid  = threadIdx.x;
    const int wave = tid >> 6;
    const int lane = tid & 63;
    const int fr   = lane & 15;
    const int kg   = lane >> 4;

    const int g  = blockIdx.x >> 4;    // global chunk (bags 1..4)
    const int mt = blockIdx.x & 15;    // m-tile (128 rows)

    int bag = 1;
#pragma unroll
    for (int b = 2; b < NBAGS; ++b)
        if (g >= args.cstart[b]) bag = b;
    const int chunk  = g - args.cstart[bag];
    const int K      = args.K[bag];
    const int kc0    = chunk * KC;
    const int nsteps = (min(kc0 + KC, K) - kc0) >> 5;   // exact: K%32==0 for bags 1..4

    const int row0 = mt * MT_BLOCK + wave * 32;
    const int* __restrict__ pA0 = args.A[bag] + (size_t)(row0 + fr) * K + kc0 + kg * 8;
    const int* __restrict__ pA1 = pA0 + (size_t)16 * K;
    const unsigned short* __restrict__ pB =
        Wp + ((size_t)(args.tstart[bag] + chunk * (KC / 64)) << 12) + (kg * LF + fr) * 8;
    const float* __restrict__ Wf = args.W[bag];

    f32x4 acc0[4], acc1[4];
#pragma unroll
    for (int i = 0; i < 4; ++i) {
        acc0[i] = (f32x4){0.f, 0.f, 0.f, 0.f};
        acc1[i] = (f32x4){0.f, 0.f, 0.f, 0.f};
    }
    int psum0 = 0, psum1 = 0;

    auto loadA = [&](int s, int4 (&x)[4]) {
        const int* p0 = pA0 + s * 32;
        const int* p1 = pA1 + s * 32;
        x[0] = *(const int4*)(p0);
        x[1] = *(const int4*)(p0 + 4);
        x[2] = *(const int4*)(p1);
        x[3] = *(const int4*)(p1 + 4);
    };
    auto loadB = [&](int s, short8 (&y)[4]) {
        if constexpr (MODE < 2) {
            const unsigned short* p = pB + (size_t)s * 2048;   // +4 KB per 32-k step
            y[0] = *(const short8*)(p);
            y[1] = *(const short8*)(p + 128);
            y[2] = *(const short8*)(p + 256);
            y[3] = *(const short8*)(p + 384);
        } else {
            const int kb = kc0 + s * 32 + kg * 8;
#pragma unroll
            for (int ni = 0; ni < 4; ++ni) {
                unsigned short t[8];
#pragma unroll
                for (int j = 0; j < 8; ++j)
                    t[j] = f2bf(Wf[(size_t)(kb + j) * LF + ni * 16 + fr]);
                y[ni] = *(short8*)t;
            }
        }
    };
    auto compute = [&](const int4 (&x)[4], const short8 (&y)[4]) {
        psum0 += x[0].x + x[0].y + x[0].z + x[0].w
               + x[1].x + x[1].y + x[1].z + x[1].w;
        psum1 += x[2].x + x[2].y + x[2].z + x[2].w
               + x[3].x + x[3].y + x[3].z + x[3].w;
        // ints are exactly {0,1}: (x | y<<16) * 0x3F80 = bf16(x) | bf16(y)<<16
        const unsigned q0 = (unsigned)(x[0].x | (x[0].y << 16)) * 0x3F80u;
        const unsigned q1 = (unsigned)(x[0].z | (x[0].w << 16)) * 0x3F80u;
        const unsigned q2 = (unsigned)(x[1].x | (x[1].y << 16)) * 0x3F80u;
        const unsigned q3 = (unsigned)(x[1].z | (x[1].w << 16)) * 0x3F80u;
        const unsigned q4 = (unsigned)(x[2].x | (x[2].y << 16)) * 0x3F80u;
        const unsigned q5 = (unsigned)(x[2].z | (x[2].w << 16)) * 0x3F80u;
        const unsigned q6 = (unsigned)(x[3].x | (x[3].y << 16)) * 0x3F80u;
        const unsigned q7 = (unsigned)(x[3].z | (x[3].w << 16)) * 0x3F80u;
        int4 u0 = make_int4((int)q0, (int)q1, (int)q2, (int)q3);
        int4 u1 = make_int4((int)q4, (int)q5, (int)q6, (int)q7);
        short8 fa0 = *(short8*)&u0;
        short8 fa1 = *(short8*)&u1;
#pragma unroll
        for (int ni = 0; ni < 4; ++ni) {
            acc0[ni] = __builtin_amdgcn_mfma_f32_16x16x32_bf16(fa0, y[ni], acc0[ni], 0, 0, 0);
            acc1[ni] = __builtin_amdgcn_mfma_f32_16x16x32_bf16(fa1, y[ni], acc1[ni], 0, 0, 0);
        }
    };

    // explicit ping-pong pipeline (depth 1, no register rotation copies)
    int4   Aa[4], Ab[4];
    short8 Ba[4], Bb[4];
    loadA(0, Aa);
    loadB(0, Ba);
    const int npair = (nsteps + 1) >> 1;
    for (int p = 0; p < npair; ++p) {
        const int s1  = 2 * p + 1;
        const int s1c = min(s1, nsteps - 1);
        loadA(s1c, Ab);
        loadB(s1c, Bb);
        __builtin_amdgcn_sched_barrier(0);
        compute(Aa, Ba);                       // step 2p (always valid)
        const int s2c = min(2 * p + 2, nsteps - 1);
        loadA(s2c, Aa);
        loadB(s2c, Ba);
        __builtin_amdgcn_sched_barrier(0);
        if (s1 < nsteps)                       // uniform branch (pad step only)
            compute(Ab, Bb);
    }

    // row popcounts: fold the 4 kg slices (lanes fr, fr+16, fr+32, fr+48)
    psum0 += __shfl_xor(psum0, 16);
    psum0 += __shfl_xor(psum0, 32);
    psum1 += __shfl_xor(psum1, 16);
    psum1 += __shfl_xor(psum1, 32);
    if (kg == 0) {
        atomicAdd(&sums[bag * BROWS + row0 + fr], psum0);
        atomicAdd(&sums[bag * BROWS + row0 + 16 + fr], psum1);
    }

    // C/D: col = lane&15 (=fr), row = kg*4 + reg   [validated R1-R3]
    if constexpr (MODE == 0) {
        float* dst = dstbuf + ((size_t)g * BROWS + row0 + kg * 4) * LF + fr;
#pragma unroll
        for (int ni = 0; ni < 4; ++ni)
#pragma unroll
            for (int r = 0; r < 4; ++r) {
                dst[(size_t)(r) * LF + ni * 16]      = acc0[ni][r];
                dst[(size_t)(16 + r) * LF + ni * 16] = acc1[ni][r];
            }
    } else {
#pragma unroll
        for (int ni = 0; ni < 4; ++ni)
#pragma unroll
            for (int r = 0; r < 4; ++r) {
                atomicAdd(dstbuf + (size_t)(row0 + kg * 4 + r) * OUTC + bag * LF + ni * 16 + fr,
                          acc0[ni][r]);
                atomicAdd(dstbuf + (size_t)(row0 + 16 + kg * 4 + r) * OUTC + bag * LF + ni * 16 + fr,
                          acc1[ni][r]);
            }
    }
}

// Sum split-K partials (or read accumulated out), apply normalization
// (incl. the faithful "decades divided twice" bug), and compute the tiny
// K=12 decades bag directly in f32.
template<bool FROMPART>
__global__ __launch_bounds__(256) void reduce_norm(BagArgs args,
                                                   const float* __restrict__ part,
                                                   float* __restrict__ out,
                                                   const int* __restrict__ sums)
{
    const int idx = blockIdx.x * 256 + threadIdx.x;
    if (idx >= BROWS * OUTC) return;
    const int row = idx / OUTC;
    const int c   = idx - row * OUTC;
    const int bag = c >> 6;
    const int col = c & 63;

    float v;
    if (bag == 0) {
        const int*   A0 = args.A[0];
        const float* W0 = args.W[0];
        float a = 0.f; int s = 0;
#pragma unroll
        for (int k = 0; k < 12; ++k) {
            const int x = A0[row * 12 + k];
            s += x;
            if (x) a += W0[k * LF + col];
        }
        if (s) a /= (float)s;
        const int sm = sums[1 * BROWS + row];     // ref bug: also divide by movie sum
        if (sm) a /= (float)sm;
        v = a;
    } else {
        if constexpr (FROMPART) {
            float a = 0.f;
            for (int gg = args.cstart[bag]; gg < args.cstart[bag + 1]; ++gg)
                a += part[((size_t)gg * BROWS + row) * LF + col];
            v = a;
        } else {
            v = out[idx];
        }
        if (bag >= 2) {
            const int s = sums[bag * BROWS + row];
            if (s) v /= (float)s;
        }
        // bag 1 (movies): never normalized (faithful to reference bug)
    }
    out[idx] = v;
}

extern "C" void kernel_launch(void* const* d_in, const int* in_sizes, int n_in,
                              void* d_out, int out_size, void* d_ws, size_t ws_size,
                              hipStream_t stream) {
    float* out = (float*)d_out;
    int* sums = (int*)d_ws;
    unsigned short* Wp = (unsigned short*)((char*)d_ws + WS_SUMS_BYTES);
    float* part = (float*)((char*)d_ws + PART_OFF);

    BagArgs args;
    const int Ks[NBAGS] = {12, 60000, 32, 100000, 20000};
    int tcum = 0;
    for (int b = 0; b < NBAGS; ++b) {
        args.A[b] = (const int*)d_in[b];
        args.W[b] = (const float*)d_in[5 + b];
        args.K[b] = Ks[b];
        args.tstart[b] = tcum;
        tcum += (Ks[b] + 63) / 64;          // -> 2816
    }
    args.tstart[NBAGS] = tcum;
    args.cstart[0] = 0;
    int ccum = 0;
    for (int b = 1; b < NBAGS; ++b) {
        args.cstart[b] = ccum;
        ccum += (Ks[b] + KC - 1) / KC;      // 30 + 1 + 49 + 10 = 90
    }
    args.cstart[NBAGS] = ccum;

    hipMemsetAsync(sums, 0, NBAGS * BROWS * sizeof(int), stream);

    const bool have_wp   = ws_size >= (size_t)WS_SUMS_BYTES + WP_BYTES;
    const bool have_part = ws_size >= PART_OFF + PART_BYTES;

    if (have_wp)
        pack_w<<<tcum / 4, 256, 0, stream>>>(args, Wp);

    dim3 grid(NCHUNKS * NMT);
    if (have_wp && have_part) {
        bag_gemm<0><<<grid, 256, 0, stream>>>(args, Wp, part, sums);
        reduce_norm<true><<<(BROWS * OUTC + 255) / 256, 256, 0, stream>>>(args, part, out, sums);
    } else if (have_wp) {
        hipMemsetAsync(d_out, 0, (size_t)out_size * sizeof(float), stream);
        bag_gemm<1><<<grid, 256, 0, stream>>>(args, Wp, out, sums);
        reduce_norm<false><<<(BROWS * OUTC + 255) / 256, 256, 0, stream>>>(args, part, out, sums);
    } else {
        hipMemsetAsync(d_out, 0, (size_t)out_size * sizeof(float), stream);
        bag_gemm<2><<<grid, 256, 0, stream>>>(args, Wp, out, sums);
        reduce_norm<false><<<(BROWS * OUTC + 255) / 256, 256, 0, stream>>>(args, part, out, sums);
    }
}